// Round 1
// baseline (749.234 us; speedup 1.0000x reference)
//
#include <hip/hip_runtime.h>
#include <hip/hip_bf16.h>

typedef __bf16 bf16;
typedef bf16 bf16x8 __attribute__((ext_vector_type(8)));
typedef float f32x16 __attribute__((ext_vector_type(16)));

#define MFMA(a,b,c) __builtin_amdgcn_mfma_f32_32x32x16_bf16(a,b,c,0,0,0)

constexpr int S = 8192;                 // n*h tokens per batch
constexpr long long SB = (long long)S * S;
constexpr long long ATTN_ELEMS = 2 * SB;

// ---------------------------------------------------------------------------
// K1: QKV projection. grid 512 x 64 threads (1 wave). 32 rows per block.
// q is pre-scaled by 1/8 (exact pow2). v is written TRANSPOSED (vt[b][d][t])
// so the PV MFMA B-fragment is a contiguous 16B load.
// ---------------------------------------------------------------------------
__global__ __launch_bounds__(64) void qkv_kernel(
    const float* __restrict__ x, const float* __restrict__ wq,
    const float* __restrict__ wk, const float* __restrict__ wv,
    bf16* __restrict__ qb, bf16* __restrict__ kb, bf16* __restrict__ vt)
{
  __shared__ bf16 vtl[64 * 34];              // [d][t] tile, stride 34 (pad)
  const int lane = threadIdx.x;
  const int lo = lane & 31, hi = lane >> 5;
  const int m0 = blockIdx.x * 32;            // global row in [0,16384)

  // A fragments: x rows -> bf16.  A[m=lane%32][k=16s+8*hi+j]
  bf16x8 af[4];
  {
    const float* xr = x + (size_t)(m0 + lo) * 64 + hi * 8;
#pragma unroll
    for (int s = 0; s < 4; ++s) {
      const float* p = xr + 16 * s;
#pragma unroll
      for (int j = 0; j < 8; ++j) af[s][j] = (bf16)p[j];
    }
  }

  const float* wmats[3] = {wq, wk, wv};
#pragma unroll 1
  for (int mat = 0; mat < 3; ++mat) {
    const float* w = wmats[mat];
#pragma unroll 1
    for (int h = 0; h < 2; ++h) {
      f32x16 acc = {};
#pragma unroll
      for (int s = 0; s < 4; ++s) {
        const float* p = w + (size_t)(32 * h + lo) * 64 + hi * 8 + 16 * s;
        bf16x8 bfr;
#pragma unroll
        for (int j = 0; j < 8; ++j) bfr[j] = (bf16)p[j];
        acc = MFMA(af[s], bfr, acc);
      }
      const int col = 32 * h + lo;
#pragma unroll
      for (int i = 0; i < 16; ++i) {
        int row = (i & 3) + 8 * (i >> 2) + 4 * hi;
        float v = acc[i];
        if (mat == 0) {
          qb[(size_t)(m0 + row) * 64 + col] = (bf16)(v * 0.125f);
        } else if (mat == 1) {
          kb[(size_t)(m0 + row) * 64 + col] = (bf16)v;
        } else {
          vtl[col * 34 + row] = (bf16)v;     // stage for transpose
        }
      }
    }
  }
  __syncthreads();
  // vt writeout: vt[b][d][t], coalesced along t
  const int b = m0 >> 13;
  const int t0 = m0 & 8191;
#pragma unroll 1
  for (int i = 0; i < 32; ++i) {
    int d = 2 * i + hi;
    vt[(size_t)b * (64 * 8192) + (size_t)d * 8192 + t0 + lo] = vtl[d * 34 + lo];
  }
}

// ---------------------------------------------------------------------------
// K2: fused attention. grid 512 x 256 threads (4 waves).
// Block = 32 q-rows of one batch.  Wave wt owns t-columns {128c+32*wt..+32}.
// Sweep 1: S=Q@K^T, l += exp(S).  Sweep 2: recompute S, write attn=exp(S)/l
// (nontemporal), P->wave-private LDS, O += P@V.  No __syncthreads in sweeps.
// ---------------------------------------------------------------------------
__global__ __launch_bounds__(256) void attn_kernel(
    const bf16* __restrict__ qb, const bf16* __restrict__ kb,
    const bf16* __restrict__ vt, float* __restrict__ attn_out,
    float* __restrict__ o_ws)
{
  __shared__ bf16 plds[4 * 32 * 40];   // per-wave 32x32 P tile, stride 40 bf16
  __shared__ float olds[32 * 65];      // O reduction buffer (pad 65)
  __shared__ float l4[4 * 32];
  __shared__ float linv[32];

  const int tid = threadIdx.x;
  const int lane = tid & 63;
  const int wt = tid >> 6;
  const int lo = lane & 31, hi = lane >> 5;

  // XCD swizzle: each XCD (bx%8) handles a single batch -> K,Vt L2-resident
  const int bx = blockIdx.x;
  const int g = bx >> 3, r = bx & 7;
  const int b = r >> 2;
  const int m0 = (g * 4 + (r & 3)) * 32;     // q-row block within batch

  for (int i = tid; i < 32 * 65; i += 256) olds[i] = 0.0f;

  // Q fragments (persist across both sweeps)
  bf16x8 qf[4];
  {
    const bf16* qr = qb + ((size_t)b * S + m0 + lo) * 64 + hi * 8;
#pragma unroll
    for (int s = 0; s < 4; ++s) qf[s] = *(const bf16x8*)(qr + 16 * s);
  }
  const bf16* kbase = kb + (size_t)b * S * 64;
  const bf16* vbase = vt + (size_t)b * 64 * S;

  // ---------------- sweep 1: row sums ----------------
  float lsum[16];
#pragma unroll
  for (int i = 0; i < 16; ++i) lsum[i] = 0.0f;
#pragma unroll 1
  for (int c = 0; c < 64; ++c) {
    const int t0 = c * 128 + wt * 32;
    f32x16 acc = {};
#pragma unroll
    for (int s = 0; s < 4; ++s) {
      bf16x8 kf = *(const bf16x8*)(kbase + (size_t)(t0 + lo) * 64 + hi * 8 + 16 * s);
      acc = MFMA(qf[s], kf, acc);
    }
#pragma unroll
    for (int i = 0; i < 16; ++i) lsum[i] += __expf(acc[i]);
  }
  // butterfly within 32-lane groups (masks <=16 stay inside each half)
#pragma unroll
  for (int i = 0; i < 16; ++i) {
    float v = lsum[i];
#pragma unroll
    for (int m = 1; m <= 16; m <<= 1) v += __shfl_xor(v, m);
    lsum[i] = v;
  }
#pragma unroll
  for (int i = 0; i < 16; ++i)
    if (lo == i) l4[wt * 32 + (i & 3) + 8 * (i >> 2) + 4 * hi] = lsum[i];
  __syncthreads();
  if (tid < 32)
    linv[tid] = 1.0f / (l4[tid] + l4[32 + tid] + l4[64 + tid] + l4[96 + tid]);
  __syncthreads();

  float linv_r[16];
#pragma unroll
  for (int i = 0; i < 16; ++i)
    linv_r[i] = linv[(i & 3) + 8 * (i >> 2) + 4 * hi];

  // ---------------- sweep 2: write attn, accumulate O ----------------
  f32x16 oacc0 = {}, oacc1 = {};
  bf16* pw = plds + wt * 1280;                     // wave-private P tile
  float* aout = attn_out + (size_t)b * SB + (size_t)m0 * S;
#pragma unroll 1
  for (int c = 0; c < 64; ++c) {
    const int t0 = c * 128 + wt * 32;
    f32x16 acc = {};
#pragma unroll
    for (int s = 0; s < 4; ++s) {
      bf16x8 kf = *(const bf16x8*)(kbase + (size_t)(t0 + lo) * 64 + hi * 8 + 16 * s);
      acc = MFMA(qf[s], kf, acc);
    }
#pragma unroll
    for (int i = 0; i < 16; ++i) {
      int row = (i & 3) + 8 * (i >> 2) + 4 * hi;
      float p = __expf(acc[i]) * linv_r[i];
      __builtin_nontemporal_store(p, aout + (size_t)row * S + t0 + lo);
      pw[row * 40 + lo] = (bf16)p;
    }
    // PV: O[32 x 64] += P(32x32) @ V(32x64); A from LDS, B = vt rows (16B)
#pragma unroll
    for (int s = 0; s < 2; ++s) {
      bf16x8 pf = *(const bf16x8*)(pw + lo * 40 + 16 * s + 8 * hi);
      bf16x8 v0 = *(const bf16x8*)(vbase + (size_t)lo * S + t0 + 16 * s + 8 * hi);
      bf16x8 v1 = *(const bf16x8*)(vbase + (size_t)(32 + lo) * S + t0 + 16 * s + 8 * hi);
      oacc0 = MFMA(pf, v0, oacc0);
      oacc1 = MFMA(pf, v1, oacc1);
    }
  }
  // reduce partial O across the 4 waves
#pragma unroll
  for (int i = 0; i < 16; ++i) {
    int row = (i & 3) + 8 * (i >> 2) + 4 * hi;
    atomicAdd(&olds[row * 65 + lo], oacc0[i]);
    atomicAdd(&olds[row * 65 + 32 + lo], oacc1[i]);
  }
  __syncthreads();
#pragma unroll
  for (int k = 0; k < 8; ++k) {
    int idx = k * 256 + tid;
    int row = idx >> 6, col = idx & 63;
    o_ws[((size_t)b * S + m0 + row) * 64 + col] = olds[row * 65 + col];
  }
}

// ---------------------------------------------------------------------------
// K3/K4: MLP with compensated bf16 MFMA (hi/lo split, 3-term products) so the
// MLP contributes ~2^-17 relative error. gelu exact via erff.
// ---------------------------------------------------------------------------
__device__ inline float gelu_exact(float v) {
  return 0.5f * v * (1.0f + erff(v * 0.70710678118654752f));
}

__global__ __launch_bounds__(256) void mlp1_kernel(
    const float* __restrict__ o_ws, const float* __restrict__ w1,
    const float* __restrict__ b1, bf16* __restrict__ hhi, bf16* __restrict__ hlo)
{
  const int tid = threadIdx.x;
  const int lane = tid & 63;
  const int wid = tid >> 6;
  const int lo = lane & 31, hi = lane >> 5;
  const int mt = blockIdx.x & 31, nt = blockIdx.x >> 5;
  const int m0 = mt * 64 + (wid & 1) * 32;
  const int f0 = nt * 64 + (wid >> 1) * 32;

  f32x16 acc = {};
  const float* arow = o_ws + (size_t)(m0 + lo) * 512 + hi * 8;
  const float* brow = w1 + (size_t)(f0 + lo) * 512 + hi * 8;
#pragma unroll 1
  for (int s = 0; s < 32; ++s) {
    const float* pa = arow + 16 * s;
    const float* pb = brow + 16 * s;
    bf16x8 ah, al, bh, bl;
#pragma unroll
    for (int j = 0; j < 8; ++j) {
      float a = pa[j];  bf16 h = (bf16)a;  ah[j] = h;  al[j] = (bf16)(a - (float)h);
      float bv = pb[j]; bf16 g = (bf16)bv; bh[j] = g;  bl[j] = (bf16)(bv - (float)g);
    }
    acc = MFMA(ah, bh, acc);
    acc = MFMA(ah, bl, acc);
    acc = MFMA(al, bh, acc);
  }
  const int f = f0 + lo;
  const float bias = b1[f];
#pragma unroll
  for (int i = 0; i < 16; ++i) {
    int m = m0 + (i & 3) + 8 * (i >> 2) + 4 * hi;
    float gv = gelu_exact(acc[i] + bias);
    bf16 h = (bf16)gv;
    hhi[(size_t)m * 1024 + f] = h;
    hlo[(size_t)m * 1024 + f] = (bf16)(gv - (float)h);
  }
}

__global__ __launch_bounds__(256) void mlp2_kernel(
    const bf16* __restrict__ hhi, const bf16* __restrict__ hlo,
    const float* __restrict__ w2, const float* __restrict__ b2,
    float* __restrict__ out2)
{
  const int tid = threadIdx.x;
  const int lane = tid & 63;
  const int wid = tid >> 6;
  const int lo = lane & 31, hi = lane >> 5;
  const int mt = blockIdx.x & 31, nt = blockIdx.x >> 5;
  const int m0 = mt * 64 + (wid & 1) * 32;
  const int e0 = nt * 64 + (wid >> 1) * 32;

  f32x16 acc = {};
  const bf16* ahr = hhi + (size_t)(m0 + lo) * 1024 + hi * 8;
  const bf16* alr = hlo + (size_t)(m0 + lo) * 1024 + hi * 8;
  const float* brow = w2 + (size_t)(e0 + lo) * 1024 + hi * 8;
#pragma unroll 1
  for (int s = 0; s < 64; ++s) {
    bf16x8 ah = *(const bf16x8*)(ahr + 16 * s);
    bf16x8 al = *(const bf16x8*)(alr + 16 * s);
    const float* pb = brow + 16 * s;
    bf16x8 bh, bl;
#pragma unroll
    for (int j = 0; j < 8; ++j) {
      float bv = pb[j]; bf16 g = (bf16)bv; bh[j] = g; bl[j] = (bf16)(bv - (float)g);
    }
    acc = MFMA(ah, bh, acc);
    acc = MFMA(al, bh, acc);
    acc = MFMA(ah, bl, acc);
  }
  const int e = e0 + lo;
  const float bias = b2[e];
#pragma unroll
  for (int i = 0; i < 16; ++i) {
    int m = m0 + (i & 3) + 8 * (i >> 2) + 4 * hi;
    out2[(size_t)m * 512 + e] = acc[i] + bias;
  }
}

// ---------------------------------------------------------------------------
extern "C" void kernel_launch(void* const* d_in, const int* in_sizes, int n_in,
                              void* d_out, int out_size, void* d_ws, size_t ws_size,
                              hipStream_t stream) {
  const float* x  = (const float*)d_in[0];
  const float* wq = (const float*)d_in[1];
  const float* wk = (const float*)d_in[2];
  const float* wv = (const float*)d_in[3];
  const float* w1 = (const float*)d_in[4];
  const float* b1 = (const float*)d_in[5];
  const float* w2 = (const float*)d_in[6];
  const float* b2 = (const float*)d_in[7];
  float* out = (float*)d_out;

  char* ws = (char*)d_ws;
  bf16* qb   = (bf16*)(ws);                       // 2 MB
  bf16* kb   = (bf16*)(ws + (2u << 20));          // 2 MB
  bf16* vtb  = (bf16*)(ws + (4u << 20));          // 2 MB (transposed V)
  float* ob  = (float*)(ws + (6u << 20));         // 4 MB (attention output)
  bf16* hhi  = (bf16*)(ws + (10u << 20));         // 4 MB
  bf16* hlo  = (bf16*)(ws + (14u << 20));         // 4 MB  -> 18 MB total

  qkv_kernel<<<512, 64, 0, stream>>>(x, wq, wk, wv, qb, kb, vtb);
  attn_kernel<<<512, 256, 0, stream>>>(qb, kb, vtb, out, ob);
  mlp1_kernel<<<512, 256, 0, stream>>>(ob, w1, b1, hhi, hlo);
  mlp2_kernel<<<256, 256, 0, stream>>>(hhi, hlo, w2, b2, out + ATTN_ELEMS);
}